// Round 14
// baseline (35.340 us; speedup 1.0000x reference)
//
#include <hip/hip_runtime.h>
#include <math.h>

#define HS    200   // HIST_SIZE
#define DIMV  64    // DIM
#define HID   32    // HIDDEN
#define NTH   256
#define NB    2     // batches per block; each batch split across 2 waves (even/odd rows)

typedef __attribute__((ext_vector_type(8))) short short8;   // 8 bf16 (4 VGPRs)
typedef __attribute__((ext_vector_type(4))) float f32x4;    // MFMA acc
typedef __bf16 bf2_t __attribute__((ext_vector_type(2)));
typedef float  f2_t  __attribute__((ext_vector_type(2)));

// packed f32x2 -> bf16x2 (RNE) -> v_cvt_pk_bf16_f32
__device__ __forceinline__ unsigned cvt2(float x, float y) {
    f2_t f = {x, y};
    bf2_t bv = __builtin_convertvector(f, bf2_t);
    union { bf2_t b; unsigned u; } un;
    un.b = bv;
    return un.u;
}

// DPP cross-lane (VALU pipe, no lgkmcnt)
template<int CTRL>
__device__ __forceinline__ float dpp_add(float x) {
    int y = __builtin_amdgcn_update_dpp(0, __float_as_int(x), CTRL, 0xF, 0xF, true);
    return x + __int_as_float(y);
}
#define ROR1  0x121
#define ROR2  0x122
#define ROR4  0x124
#define ROR8  0x128
#define QXOR1 0xB1   // quad_perm [1,0,3,2]
#define QXOR2 0x4E   // quad_perm [2,3,0,1]
#define HMIRR 0x141  // row_half_mirror (lane ^ 7 within 8)
__device__ __forceinline__ float swz_xor16(float x) {  // lane ^ 16 (within 32)
    return __int_as_float(__builtin_amdgcn_ds_swizzle(__float_as_int(x), 0x401F));
}
__device__ __forceinline__ float rfl(float x) {        // wave-uniform broadcast
    return __int_as_float(__builtin_amdgcn_readfirstlane(__float_as_int(x)));
}

// s_Mt[k]: 32 rows (h) x 64 ushort (f), 16-B groups XOR-swizzled by (h&7).

__global__ __launch_bounds__(NTH, 4) void din_attn_kernel(
    const float* __restrict__ cand,   // B x 64
    const float* __restrict__ hist,   // B x 200 x 64
    const int*   __restrict__ lens,   // B
    const float* __restrict__ W1,     // 256 x 32
    const float* __restrict__ B1,     // 32
    const float* __restrict__ W2,     // 32
    const float* __restrict__ B2,     // 1 (uniform shift cancels in softmax)
    float* __restrict__ out)          // B x 64
{
    __shared__ __align__(16) unsigned short s_Mt[NB][HID * 64];  // 8192 B
    __shared__ float s_c[NB][HID];                               // 256 B
    __shared__ __align__(16) float s_comb[4][DIMV];              // 1024 B
    __shared__ float s_m[4], s_l[4];                             // 32 B

    const int tid  = threadIdx.x;
    const int lane = tid & 63, wid = tid >> 6;
    const int b0   = blockIdx.x * NB;

    // ---------------- Phase A (cooperative, one barrier) ------------------------
    {   // Mt[k][h][f] = bf16(Wb - Wd + cand_k[f]*Wc); W1 slices loaded once
        const int h = tid & 31, fg = tid >> 5;       // f = fg*8 .. fg*8+7
        float wbd[8], wcc[8];
        #pragma unroll
        for (int ff = 0; ff < 8; ++ff) {
            int f = fg * 8 + ff;
            wbd[ff] = W1[(DIMV + f) * HID + h] - W1[(3 * DIMV + f) * HID + h];
            wcc[ff] = W1[(2 * DIMV + f) * HID + h];
        }
        #pragma unroll
        for (int k = 0; k < NB; ++k) {
            const float* cb = cand + (size_t)(b0 + k) * DIMV + fg * 8;
            float4 cA = *(const float4*)cb;
            float4 cB = *(const float4*)(cb + 4);
            float cf[8] = {cA.x, cA.y, cA.z, cA.w, cB.x, cB.y, cB.z, cB.w};
            float m[8];
            #pragma unroll
            for (int ff = 0; ff < 8; ++ff) m[ff] = fmaf(cf[ff], wcc[ff], wbd[ff]);
            uint4 mw = make_uint4(cvt2(m[0], m[1]), cvt2(m[2], m[3]),
                                  cvt2(m[4], m[5]), cvt2(m[6], m[7]));
            *(uint4*)&s_Mt[k][h * 64 + (fg ^ (h & 7)) * 8] = mw;
        }
        // c[k][h] = cand_k · (Wa+Wd)[:,h] + B1[h]; 8 threads per h
        const int hc = tid >> 3, fgc = tid & 7;
        float wad[8];
        #pragma unroll
        for (int ff = 0; ff < 8; ++ff) {
            int f = fgc * 8 + ff;
            wad[ff] = W1[f * HID + hc] + W1[(3 * DIMV + f) * HID + hc];
        }
        float b1 = B1[hc];
        #pragma unroll
        for (int k = 0; k < NB; ++k) {
            const float* cb = cand + (size_t)(b0 + k) * DIMV + fgc * 8;
            float4 cA = *(const float4*)cb;
            float4 cB = *(const float4*)(cb + 4);
            float p = cA.x * wad[0] + cA.y * wad[1] + cA.z * wad[2] + cA.w * wad[3]
                    + cB.x * wad[4] + cB.y * wad[5] + cB.z * wad[6] + cB.w * wad[7];
            p = dpp_add<QXOR1>(p);
            p = dpp_add<QXOR2>(p);
            p = dpp_add<HMIRR>(p);
            if ((tid & 7) == 0) s_c[k][hc] = p + b1;
        }
    }
    __syncthreads();

    // ---------------- per-wave flash loop over its HALF-batch -------------------
    // wave -> (batch kb = wid>>1, half hf = wid&1); rows hf, hf+2, hf+4, ...
    const int kb   = wid >> 1, hf = wid & 1;
    const int b    = b0 + kb;
    const int len  = lens[b];
    const bool uni = (len == 0);
    const int nrow  = uni ? HS : len;          // len==0: uniform mean over all rows
    const int nhalf = (nrow + 1 - hf) >> 1;    // rows in this half (round-robin)
    const int nt    = (nhalf + 15) >> 4;
    const int lc    = lane & 15, lg = lane >> 4;
    const float* hb = hist + (size_t)b * (HS * DIMV);

    short8 b00 = *(const short8*)&s_Mt[kb][lc * 64        + ((lg)     ^ (lc & 7)) * 8];
    short8 b01 = *(const short8*)&s_Mt[kb][lc * 64        + ((4 + lg) ^ (lc & 7)) * 8];
    short8 b10 = *(const short8*)&s_Mt[kb][(16 + lc) * 64 + ((lg)     ^ (lc & 7)) * 8];
    short8 b11 = *(const short8*)&s_Mt[kb][(16 + lc) * 64 + ((4 + lg) ^ (lc & 7)) * 8];
    const float c0  = s_c[kb][lc],     c1  = s_c[kb][16 + lc];
    const float w20 = W2[lc] * 0.125f, w21 = W2[16 + lc] * 0.125f;  // fold 1/sqrt(64)

    float m_run = -3.0e38f, l_acc = 0.f;
    float o0[8] = {0.f, 0.f, 0.f, 0.f, 0.f, 0.f, 0.f, 0.f};
    float o1[8] = {0.f, 0.f, 0.f, 0.f, 0.f, 0.f, 0.f, 0.f};

    for (int rt = 0; rt < nt; ++rt) {         // wave-uniform trip count
        int i = rt * 16 + lc;                 // half-local row index
        if (i > nhalf - 1) i = nhalf - 1;     // clamp (dup row; weight forced 0)
        const int s = 2 * i + hf;             // actual hist row
        const float* ap = hb + s * 64 + lg * 8;
        float4 A00 = *(const float4*)ap;
        float4 A01 = *(const float4*)(ap + 4);
        float4 A10 = *(const float4*)(ap + 32);
        float4 A11 = *(const float4*)(ap + 36);
        union { uint4 u; short8 s8; } u0, u1;
        u0.u = make_uint4(cvt2(A00.x, A00.y), cvt2(A00.z, A00.w),
                          cvt2(A01.x, A01.y), cvt2(A01.z, A01.w));
        u1.u = make_uint4(cvt2(A10.x, A10.y), cvt2(A10.z, A10.w),
                          cvt2(A11.x, A11.y), cvt2(A11.z, A11.w));

        f32x4 acc0 = {c0, c0, c0, c0};
        acc0 = __builtin_amdgcn_mfma_f32_16x16x32_bf16(u0.s8, b00, acc0, 0, 0, 0);
        acc0 = __builtin_amdgcn_mfma_f32_16x16x32_bf16(u1.s8, b01, acc0, 0, 0, 0);
        f32x4 acc1 = {c1, c1, c1, c1};
        acc1 = __builtin_amdgcn_mfma_f32_16x16x32_bf16(u0.s8, b10, acc1, 0, 0, 0);
        acc1 = __builtin_amdgcn_mfma_f32_16x16x32_bf16(u1.s8, b11, acc1, 0, 0, 0);

        float p[4];
        #pragma unroll
        for (int r = 0; r < 4; ++r)
            p[r] = fmaxf(acc0[r], 0.f) * w20 + fmaxf(acc1[r], 0.f) * w21;  // scaled
        #pragma unroll
        for (int r = 0; r < 4; ++r) {         // cyclic 16-lane reduce: ALL lanes get sum
            p[r] = dpp_add<ROR1>(p[r]);
            p[r] = dpp_add<ROR2>(p[r]);
            p[r] = dpp_add<ROR4>(p[r]);
            p[r] = dpp_add<ROR8>(p[r]);
        }
        #pragma unroll
        for (int r = 0; r < 4; ++r) {         // mask (half-local) + uniform override
            int row = rt * 16 + lg * 4 + r;
            p[r] = (row < nhalf) ? (uni ? 0.f : p[r]) : -4.0e9f;
        }
        float tmax = fmaxf(fmaxf(p[0], p[1]), fmaxf(p[2], p[3]));
        tmax = fmaxf(tmax, swz_xor16(tmax));
        tmax = fmaxf(tmax, __shfl_xor(tmax, 32));
        tmax = rfl(tmax);                     // exec-uniform running max decision
        if (tmax > m_run + 8.f) {             // T13 defer-rescale
            float sf = __expf(m_run - tmax);
            #pragma unroll
            for (int j = 0; j < 8; ++j) { o0[j] *= sf; o1[j] *= sf; }
            l_acc *= sf;
            m_run = tmax;
        }
        float e[4];
        #pragma unroll
        for (int r = 0; r < 4; ++r) e[r] = __expf(p[r] - m_run);  // masked -> 0
        l_acc += (e[0] + e[1]) + (e[2] + e[3]);

        // weight for THIS lane's half-local row (= lc within tile)
        float t0 = (lc & 1) ? e[1] : e[0];
        float t1 = (lc & 1) ? e[3] : e[2];
        float es = (lc & 2) ? t1 : t0;
        int   src = (((lc & 3) | ((lc >> 2) << 4)) << 2);
        float wrow = __int_as_float(
            __builtin_amdgcn_ds_bpermute(src, __float_as_int(es)));

        o0[0] = fmaf(wrow, A00.x, o0[0]); o0[1] = fmaf(wrow, A00.y, o0[1]);
        o0[2] = fmaf(wrow, A00.z, o0[2]); o0[3] = fmaf(wrow, A00.w, o0[3]);
        o0[4] = fmaf(wrow, A01.x, o0[4]); o0[5] = fmaf(wrow, A01.y, o0[5]);
        o0[6] = fmaf(wrow, A01.z, o0[6]); o0[7] = fmaf(wrow, A01.w, o0[7]);
        o1[0] = fmaf(wrow, A10.x, o1[0]); o1[1] = fmaf(wrow, A10.y, o1[1]);
        o1[2] = fmaf(wrow, A10.z, o1[2]); o1[3] = fmaf(wrow, A10.w, o1[3]);
        o1[4] = fmaf(wrow, A11.x, o1[4]); o1[5] = fmaf(wrow, A11.y, o1[5]);
        o1[6] = fmaf(wrow, A11.z, o1[6]); o1[7] = fmaf(wrow, A11.w, o1[7]);
    }

    // ---------------- per-wave partial: reduce & publish (UNNORMALIZED) ---------
    l_acc += swz_xor16(l_acc);
    l_acc += __shfl_xor(l_acc, 32);
    #pragma unroll
    for (int j = 0; j < 8; ++j) {             // sum over the 16 rows (lc) per lg
        float x = o0[j];
        x = dpp_add<ROR1>(x); x = dpp_add<ROR2>(x);
        x = dpp_add<ROR4>(x); x = dpp_add<ROR8>(x);
        o0[j] = x;
        float y = o1[j];
        y = dpp_add<ROR1>(y); y = dpp_add<ROR2>(y);
        y = dpp_add<ROR4>(y); y = dpp_add<ROR8>(y);
        o1[j] = y;
    }
    if (lc == 0) {                            // lanes 0,16,32,48
        float* d = &s_comb[wid][lg * 8];
        *(float4*)d        = make_float4(o0[0], o0[1], o0[2], o0[3]);
        *(float4*)(d + 4)  = make_float4(o0[4], o0[5], o0[6], o0[7]);
        *(float4*)(d + 32) = make_float4(o1[0], o1[1], o1[2], o1[3]);
        *(float4*)(d + 36) = make_float4(o1[4], o1[5], o1[6], o1[7]);
        if (lane == 0) { s_m[wid] = m_run; s_l[wid] = l_acc; }
    }
    __syncthreads();

    // ---------------- flash combine (fixed order -> deterministic) --------------
    if (wid < NB) {                           // wave wid combines batch b0+wid
        const int w0 = 2 * wid, w1 = 2 * wid + 1;
        const float m0 = s_m[w0], m1 = s_m[w1];
        const float M  = fmaxf(m0, m1);
        const float a0 = __expf(m0 - M), a1 = __expf(m1 - M);
        const float den = a0 * s_l[w0] + a1 * s_l[w1];
        const float o   = a0 * s_comb[w0][lane] + a1 * s_comb[w1][lane];
        out[(size_t)(b0 + wid) * DIMV + lane] = o / den;
    }
}

extern "C" void kernel_launch(void* const* d_in, const int* in_sizes, int n_in,
                              void* d_out, int out_size, void* d_ws, size_t ws_size,
                              hipStream_t stream) {
    const float* cand = (const float*)d_in[0];
    const float* hist = (const float*)d_in[1];
    const int*   lens = (const int*)d_in[2];
    const float* W1   = (const float*)d_in[3];
    const float* B1   = (const float*)d_in[4];
    const float* W2   = (const float*)d_in[5];
    const float* B2   = (const float*)d_in[6];
    float* out = (float*)d_out;

    const int B = in_sizes[0] / DIMV;     // 4096
    const int GRID = B / NB;              // 2048 blocks; 4 resident/CU -> backfill
    din_attn_kernel<<<GRID, NTH, 0, stream>>>(cand, hist, lens, W1, B1, W2, B2, out);
}

// Round 15
// 32.991 us; speedup vs baseline: 1.0712x; 1.0712x over previous
//
#include <hip/hip_runtime.h>
#include <math.h>

#define HS    200   // HIST_SIZE
#define DIMV  64    // DIM
#define HID   32    // HIDDEN
#define NTH   256
#define NB    4     // batches per block; tiles distributed to waves via LDS queue

typedef __attribute__((ext_vector_type(8))) short short8;   // 8 bf16 (4 VGPRs)
typedef __attribute__((ext_vector_type(4))) float f32x4;    // MFMA acc
typedef __bf16 bf2_t __attribute__((ext_vector_type(2)));
typedef float  f2_t  __attribute__((ext_vector_type(2)));

// packed f32x2 -> bf16x2 (RNE) -> v_cvt_pk_bf16_f32
__device__ __forceinline__ unsigned cvt2(float x, float y) {
    f2_t f = {x, y};
    bf2_t bv = __builtin_convertvector(f, bf2_t);
    union { bf2_t b; unsigned u; } un;
    un.b = bv;
    return un.u;
}
__device__ __forceinline__ float blo(unsigned u) { return __uint_as_float(u << 16); }
__device__ __forceinline__ float bhi(unsigned u) { return __uint_as_float(u & 0xFFFF0000u); }

// DPP cross-lane (VALU pipe, no lgkmcnt)
template<int CTRL>
__device__ __forceinline__ float dpp_add(float x) {
    int y = __builtin_amdgcn_update_dpp(0, __float_as_int(x), CTRL, 0xF, 0xF, true);
    return x + __int_as_float(y);
}
#define ROR1  0x121
#define ROR2  0x122
#define ROR4  0x124
#define ROR8  0x128
#define QXOR1 0xB1   // quad_perm [1,0,3,2]
#define QXOR2 0x4E   // quad_perm [2,3,0,1]
#define HMIRR 0x141  // row_half_mirror (lane ^ 7 within 8)
__device__ __forceinline__ float swz_xor16(float x) {  // lane ^ 16 (within 32)
    return __int_as_float(__builtin_amdgcn_ds_swizzle(__float_as_int(x), 0x401F));
}
__device__ __forceinline__ float rfl(float x) {        // wave-uniform broadcast
    return __int_as_float(__builtin_amdgcn_readfirstlane(__float_as_int(x)));
}

// s_Mt[k]: 32 rows (h) x 64 ushort (f), 16-B groups XOR-swizzled by (h&7).

__global__ __launch_bounds__(NTH, 4) void din_attn_kernel(
    const float* __restrict__ cand,   // B x 64
    const float* __restrict__ hist,   // B x 200 x 64
    const int*   __restrict__ lens,   // B
    const float* __restrict__ W1,     // 256 x 32
    const float* __restrict__ B1,     // 32
    const float* __restrict__ W2,     // 32
    const float* __restrict__ B2,     // 1 (uniform shift cancels in softmax)
    float* __restrict__ out)          // B x 64
{
    __shared__ __align__(16) unsigned short s_Mt[NB][HID * 64];  // 16384 B
    __shared__ float s_c[NB][HID];                               // 512 B
    __shared__ __align__(16) float s_om[4][NB][DIMV];            // 4096 B
    __shared__ float s_mm[4][NB], s_ll[4][NB];                   // 128 B
    __shared__ int   s_ctr;

    const int tid  = threadIdx.x;
    const int lane = tid & 63, wid = tid >> 6;
    const int b0   = blockIdx.x * NB;

    // ---------------- Phase A (cooperative, one barrier) ------------------------
    {   // Mt[k][h][f] = bf16(Wb - Wd + cand_k[f]*Wc); W1 slices loaded once
        const int h = tid & 31, fg = tid >> 5;       // f = fg*8 .. fg*8+7
        float wbd[8], wcc[8];
        #pragma unroll
        for (int ff = 0; ff < 8; ++ff) {
            int f = fg * 8 + ff;
            wbd[ff] = W1[(DIMV + f) * HID + h] - W1[(3 * DIMV + f) * HID + h];
            wcc[ff] = W1[(2 * DIMV + f) * HID + h];
        }
        #pragma unroll
        for (int k = 0; k < NB; ++k) {
            const float* cb = cand + (size_t)(b0 + k) * DIMV + fg * 8;
            float4 cA = *(const float4*)cb;
            float4 cB = *(const float4*)(cb + 4);
            float cf[8] = {cA.x, cA.y, cA.z, cA.w, cB.x, cB.y, cB.z, cB.w};
            float m[8];
            #pragma unroll
            for (int ff = 0; ff < 8; ++ff) m[ff] = fmaf(cf[ff], wcc[ff], wbd[ff]);
            uint4 mw = make_uint4(cvt2(m[0], m[1]), cvt2(m[2], m[3]),
                                  cvt2(m[4], m[5]), cvt2(m[6], m[7]));
            *(uint4*)&s_Mt[k][h * 64 + (fg ^ (h & 7)) * 8] = mw;
        }
        // c[k][h] = cand_k · (Wa+Wd)[:,h] + B1[h]; 8 threads per h
        const int hc = tid >> 3, fgc = tid & 7;
        float wad[8];
        #pragma unroll
        for (int ff = 0; ff < 8; ++ff) {
            int f = fgc * 8 + ff;
            wad[ff] = W1[f * HID + hc] + W1[(3 * DIMV + f) * HID + hc];
        }
        float b1 = B1[hc];
        #pragma unroll
        for (int k = 0; k < NB; ++k) {
            const float* cb = cand + (size_t)(b0 + k) * DIMV + fgc * 8;
            float4 cA = *(const float4*)cb;
            float4 cB = *(const float4*)(cb + 4);
            float p = cA.x * wad[0] + cA.y * wad[1] + cA.z * wad[2] + cA.w * wad[3]
                    + cB.x * wad[4] + cB.y * wad[5] + cB.z * wad[6] + cB.w * wad[7];
            p = dpp_add<QXOR1>(p);
            p = dpp_add<QXOR2>(p);
            p = dpp_add<HMIRR>(p);
            if ((tid & 7) == 0) s_c[k][hc] = p + b1;
        }
        if (tid < 16) { s_mm[tid >> 2][tid & 3] = -3.0e38f; s_ll[tid >> 2][tid & 3] = 0.f; }
        if (tid == 0) s_ctr = 0;
    }
    __syncthreads();

    // ---------------- batch metadata (wave-uniform scalars) ---------------------
    const int lc = lane & 15, lg = lane >> 4;
    const float w20 = W2[lc] * 0.125f, w21 = W2[16 + lc] * 0.125f;  // fold 1/sqrt(64)
    const int len0 = lens[b0 + 0], len1 = lens[b0 + 1];
    const int len2 = lens[b0 + 2], len3 = lens[b0 + 3];
    const int nr0 = (len0 == 0) ? HS : len0, nr1 = (len1 == 0) ? HS : len1;
    const int nr2 = (len2 == 0) ? HS : len2, nr3 = (len3 == 0) ? HS : len3;
    const int t0 = (nr0 + 15) >> 4, t1 = (nr1 + 15) >> 4;
    const int t2 = (nr2 + 15) >> 4, t3 = (nr3 + 15) >> 4;
    const int q1 = t0, q2 = t0 + t1, q3 = t0 + t1 + t2;
    const int total = q3 + t3;

    // ---------------- work-stealing flash loop ----------------------------------
    int curk = -1, nrow = 0;
    bool uni = false;
    float c0 = 0.f, c1 = 0.f;
    float m_run = -3.0e38f, l_acc = 0.f;
    float o0[8] = {0.f, 0.f, 0.f, 0.f, 0.f, 0.f, 0.f, 0.f};
    float o1[8] = {0.f, 0.f, 0.f, 0.f, 0.f, 0.f, 0.f, 0.f};
    const float* hb = hist;

    auto FLUSH = [&](int kk) {
        float l = l_acc;
        l += swz_xor16(l);
        l += __shfl_xor(l, 32);
        #pragma unroll
        for (int jj = 0; jj < 8; ++jj) {
            float x = o0[jj];
            x = dpp_add<ROR1>(x); x = dpp_add<ROR2>(x);
            x = dpp_add<ROR4>(x); x = dpp_add<ROR8>(x);
            o0[jj] = x;
            float y = o1[jj];
            y = dpp_add<ROR1>(y); y = dpp_add<ROR2>(y);
            y = dpp_add<ROR4>(y); y = dpp_add<ROR8>(y);
            o1[jj] = y;
        }
        if (lc == 0) {                    // lanes 0,16,32,48
            float* d = &s_om[wid][kk][lg * 8];
            *(float4*)d        = make_float4(o0[0], o0[1], o0[2], o0[3]);
            *(float4*)(d + 4)  = make_float4(o0[4], o0[5], o0[6], o0[7]);
            *(float4*)(d + 32) = make_float4(o1[0], o1[1], o1[2], o1[3]);
            *(float4*)(d + 36) = make_float4(o1[4], o1[5], o1[6], o1[7]);
            if (lane == 0) { s_mm[wid][kk] = m_run; s_ll[wid][kk] = l; }
        }
    };

    for (;;) {
        int j = 0;
        if (lane == 0) j = atomicAdd(&s_ctr, 1);
        j = __shfl(j, 0);                 // wave-uniform tile index
        if (j >= total) break;
        const int k  = (j >= q1) + (j >= q2) + (j >= q3);
        const int rt = j - ((k == 0) ? 0 : (k == 1) ? q1 : (k == 2) ? q2 : q3);
        if (k != curk) {
            if (curk >= 0) FLUSH(curk);
            curk = k;
            m_run = -3.0e38f; l_acc = 0.f;
            #pragma unroll
            for (int jj = 0; jj < 8; ++jj) { o0[jj] = 0.f; o1[jj] = 0.f; }
            c0 = s_c[k][lc]; c1 = s_c[k][16 + lc];
            const int lk = (k == 0) ? len0 : (k == 1) ? len1 : (k == 2) ? len2 : len3;
            uni  = (lk == 0);
            nrow = (k == 0) ? nr0 : (k == 1) ? nr1 : (k == 2) ? nr2 : nr3;
            hb   = hist + (size_t)(b0 + k) * (HS * DIMV);
        }

        int i = rt * 16 + lc;
        if (i > nrow - 1) i = nrow - 1;   // clamp (dup row; weight forced 0)
        const float* ap = hb + i * 64 + lg * 8;
        float4 A00 = *(const float4*)ap;
        float4 A01 = *(const float4*)(ap + 4);
        float4 A10 = *(const float4*)(ap + 32);
        float4 A11 = *(const float4*)(ap + 36);
        union { uint4 u; short8 s8; } u0, u1;
        u0.u = make_uint4(cvt2(A00.x, A00.y), cvt2(A00.z, A00.w),
                          cvt2(A01.x, A01.y), cvt2(A01.z, A01.w));
        u1.u = make_uint4(cvt2(A10.x, A10.y), cvt2(A10.z, A10.w),
                          cvt2(A11.x, A11.y), cvt2(A11.z, A11.w));

        const unsigned short* mt = s_Mt[k];
        short8 b00 = *(const short8*)&mt[lc * 64        + ((lg)     ^ (lc & 7)) * 8];
        short8 b01 = *(const short8*)&mt[lc * 64        + ((4 + lg) ^ (lc & 7)) * 8];
        short8 b10 = *(const short8*)&mt[(16 + lc) * 64 + ((lg)     ^ (lc & 7)) * 8];
        short8 b11 = *(const short8*)&mt[(16 + lc) * 64 + ((4 + lg) ^ (lc & 7)) * 8];

        f32x4 acc0 = {c0, c0, c0, c0};
        acc0 = __builtin_amdgcn_mfma_f32_16x16x32_bf16(u0.s8, b00, acc0, 0, 0, 0);
        acc0 = __builtin_amdgcn_mfma_f32_16x16x32_bf16(u1.s8, b01, acc0, 0, 0, 0);
        f32x4 acc1 = {c1, c1, c1, c1};
        acc1 = __builtin_amdgcn_mfma_f32_16x16x32_bf16(u0.s8, b10, acc1, 0, 0, 0);
        acc1 = __builtin_amdgcn_mfma_f32_16x16x32_bf16(u1.s8, b11, acc1, 0, 0, 0);

        float p[4];
        #pragma unroll
        for (int r = 0; r < 4; ++r)
            p[r] = fmaxf(acc0[r], 0.f) * w20 + fmaxf(acc1[r], 0.f) * w21;
        #pragma unroll
        for (int r = 0; r < 4; ++r) {     // cyclic 16-lane reduce: ALL lanes get sum
            p[r] = dpp_add<ROR1>(p[r]);
            p[r] = dpp_add<ROR2>(p[r]);
            p[r] = dpp_add<ROR4>(p[r]);
            p[r] = dpp_add<ROR8>(p[r]);
        }
        #pragma unroll
        for (int r = 0; r < 4; ++r) {     // mask + uniform override
            int row = rt * 16 + lg * 4 + r;
            p[r] = (row < nrow) ? (uni ? 0.f : p[r]) : -4.0e9f;
        }
        float tmax = fmaxf(fmaxf(p[0], p[1]), fmaxf(p[2], p[3]));
        tmax = fmaxf(tmax, swz_xor16(tmax));
        tmax = fmaxf(tmax, __shfl_xor(tmax, 32));
        tmax = rfl(tmax);
        if (tmax > m_run + 8.f) {         // T13 defer-rescale
            float sf = __expf(m_run - tmax);
            #pragma unroll
            for (int jj = 0; jj < 8; ++jj) { o0[jj] *= sf; o1[jj] *= sf; }
            l_acc *= sf;
            m_run = tmax;
        }
        float e[4];
        #pragma unroll
        for (int r = 0; r < 4; ++r) e[r] = __expf(p[r] - m_run);  // masked -> 0
        l_acc += (e[0] + e[1]) + (e[2] + e[3]);

        // weight for THIS lane's row (tile row lc)
        float s0 = (lc & 1) ? e[1] : e[0];
        float s1 = (lc & 1) ? e[3] : e[2];
        float es = (lc & 2) ? s1 : s0;
        int   src = (((lc & 3) | ((lc >> 2) << 4)) << 2);
        float wrow = __int_as_float(
            __builtin_amdgcn_ds_bpermute(src, __float_as_int(es)));

        o0[0] = fmaf(wrow, blo(u0.u.x), o0[0]); o0[1] = fmaf(wrow, bhi(u0.u.x), o0[1]);
        o0[2] = fmaf(wrow, blo(u0.u.y), o0[2]); o0[3] = fmaf(wrow, bhi(u0.u.y), o0[3]);
        o0[4] = fmaf(wrow, blo(u0.u.z), o0[4]); o0[5] = fmaf(wrow, bhi(u0.u.z), o0[5]);
        o0[6] = fmaf(wrow, blo(u0.u.w), o0[6]); o0[7] = fmaf(wrow, bhi(u0.u.w), o0[7]);
        o1[0] = fmaf(wrow, blo(u1.u.x), o1[0]); o1[1] = fmaf(wrow, bhi(u1.u.x), o1[1]);
        o1[2] = fmaf(wrow, blo(u1.u.y), o1[2]); o1[3] = fmaf(wrow, bhi(u1.u.y), o1[3]);
        o1[4] = fmaf(wrow, blo(u1.u.z), o1[4]); o1[5] = fmaf(wrow, bhi(u1.u.z), o1[5]);
        o1[6] = fmaf(wrow, blo(u1.u.w), o1[6]); o1[7] = fmaf(wrow, bhi(u1.u.w), o1[7]);
    }
    if (curk >= 0) FLUSH(curk);
    __syncthreads();

    // ---------------- flash combine (fixed order -> deterministic) --------------
    {   // wave wid combines batch b0+wid over wave-slots 0..3
        const float m0 = s_mm[0][wid], m1 = s_mm[1][wid];
        const float m2 = s_mm[2][wid], m3 = s_mm[3][wid];
        const float M  = fmaxf(fmaxf(m0, m1), fmaxf(m2, m3));
        const float a0 = __expf(m0 - M), a1 = __expf(m1 - M);
        const float a2 = __expf(m2 - M), a3 = __expf(m3 - M);
        const float den = a0 * s_ll[0][wid] + a1 * s_ll[1][wid]
                        + a2 * s_ll[2][wid] + a3 * s_ll[3][wid];
        const float o = a0 * s_om[0][wid][lane] + a1 * s_om[1][wid][lane]
                      + a2 * s_om[2][wid][lane] + a3 * s_om[3][wid][lane];
        out[(size_t)(b0 + wid) * DIMV + lane] = o / den;
    }
}

extern "C" void kernel_launch(void* const* d_in, const int* in_sizes, int n_in,
                              void* d_out, int out_size, void* d_ws, size_t ws_size,
                              hipStream_t stream) {
    const float* cand = (const float*)d_in[0];
    const float* hist = (const float*)d_in[1];
    const int*   lens = (const int*)d_in[2];
    const float* W1   = (const float*)d_in[3];
    const float* B1   = (const float*)d_in[4];
    const float* W2   = (const float*)d_in[5];
    const float* B2   = (const float*)d_in[6];
    float* out = (float*)d_out;

    const int B = in_sizes[0] / DIMV;     // 4096
    const int GRID = B / NB;              // 1024 blocks; 4/CU -> one resident round
    din_attn_kernel<<<GRID, NTH, 0, stream>>>(cand, hist, lens, W1, B1, W2, B2, out);
}

// Round 16
// 31.469 us; speedup vs baseline: 1.1230x; 1.0484x over previous
//
#include <hip/hip_runtime.h>
#include <math.h>

#define HS    200   // HIST_SIZE
#define DIMV  64    // DIM
#define HID   32    // HIDDEN
#define NTH   256
#define NBPB  4     // batches per block == waves per block (wave-per-batch)

typedef __attribute__((ext_vector_type(8))) short short8;   // 8 bf16 (4 VGPRs)
typedef __attribute__((ext_vector_type(4))) float f32x4;    // MFMA acc
typedef __bf16 bf2_t __attribute__((ext_vector_type(2)));
typedef float  f2_t  __attribute__((ext_vector_type(2)));

// packed f32x2 -> bf16x2 (RNE) -> v_cvt_pk_bf16_f32
__device__ __forceinline__ unsigned cvt2(float x, float y) {
    f2_t f = {x, y};
    bf2_t bv = __builtin_convertvector(f, bf2_t);
    union { bf2_t b; unsigned u; } un;
    un.b = bv;
    return un.u;
}

// DPP cross-lane (VALU pipe, no lgkmcnt)
template<int CTRL>
__device__ __forceinline__ float dpp_add(float x) {
    int y = __builtin_amdgcn_update_dpp(0, __float_as_int(x), CTRL, 0xF, 0xF, true);
    return x + __int_as_float(y);
}
#define ROR1  0x121
#define ROR2  0x122
#define ROR4  0x124
#define ROR8  0x128
#define QXOR1 0xB1   // quad_perm [1,0,3,2]
#define QXOR2 0x4E   // quad_perm [2,3,0,1]
#define HMIRR 0x141  // row_half_mirror (lane ^ 7 within 8)
__device__ __forceinline__ float swz_xor16(float x) {  // lane ^ 16 (within 32)
    return __int_as_float(__builtin_amdgcn_ds_swizzle(__float_as_int(x), 0x401F));
}
__device__ __forceinline__ float rfl(float x) {        // wave-uniform broadcast
    return __int_as_float(__builtin_amdgcn_readfirstlane(__float_as_int(x)));
}

// s_Mt[k]: 32 rows (h) x 64 ushort (f), 16-B groups XOR-swizzled by (h&7).

__global__ __launch_bounds__(NTH, 4) void din_attn_kernel(
    const float* __restrict__ cand,   // B x 64
    const float* __restrict__ hist,   // B x 200 x 64
    const int*   __restrict__ lens,   // B
    const float* __restrict__ W1,     // 256 x 32
    const float* __restrict__ B1,     // 32
    const float* __restrict__ W2,     // 32
    const float* __restrict__ B2,     // 1 (uniform shift cancels in softmax)
    float* __restrict__ out)          // B x 64
{
    __shared__ __align__(16) unsigned short s_Mt[NBPB][HID * 64];  // 16384 B
    __shared__ float s_c[NBPB][HID];                               // 512 B

    const int tid  = threadIdx.x;
    const int lane = tid & 63, wid = tid >> 6;
    const int b0   = blockIdx.x * NBPB;

    // ---------------- Phase A (cooperative, one barrier) ------------------------
    {   // Mt[k][h][f] = bf16(Wb - Wd + cand_k[f]*Wc); W1 slices loaded once
        const int h = tid & 31, fg = tid >> 5;       // f = fg*8 .. fg*8+7
        float wbd[8], wcc[8];
        #pragma unroll
        for (int ff = 0; ff < 8; ++ff) {
            int f = fg * 8 + ff;
            wbd[ff] = W1[(DIMV + f) * HID + h] - W1[(3 * DIMV + f) * HID + h];
            wcc[ff] = W1[(2 * DIMV + f) * HID + h];
        }
        #pragma unroll
        for (int k = 0; k < NBPB; ++k) {
            const float* cb = cand + (size_t)(b0 + k) * DIMV + fg * 8;
            float4 cA = *(const float4*)cb;
            float4 cB = *(const float4*)(cb + 4);
            float cf[8] = {cA.x, cA.y, cA.z, cA.w, cB.x, cB.y, cB.z, cB.w};
            float m[8];
            #pragma unroll
            for (int ff = 0; ff < 8; ++ff) m[ff] = fmaf(cf[ff], wcc[ff], wbd[ff]);
            uint4 mw = make_uint4(cvt2(m[0], m[1]), cvt2(m[2], m[3]),
                                  cvt2(m[4], m[5]), cvt2(m[6], m[7]));
            *(uint4*)&s_Mt[k][h * 64 + (fg ^ (h & 7)) * 8] = mw;
        }
        // c[k][h] = cand_k · (Wa+Wd)[:,h] + B1[h]; 8 threads per h
        const int hc = tid >> 3, fgc = tid & 7;
        float wad[8];
        #pragma unroll
        for (int ff = 0; ff < 8; ++ff) {
            int f = fgc * 8 + ff;
            wad[ff] = W1[f * HID + hc] + W1[(3 * DIMV + f) * HID + hc];
        }
        float b1 = B1[hc];
        #pragma unroll
        for (int k = 0; k < NBPB; ++k) {
            const float* cb = cand + (size_t)(b0 + k) * DIMV + fgc * 8;
            float4 cA = *(const float4*)cb;
            float4 cB = *(const float4*)(cb + 4);
            float p = cA.x * wad[0] + cA.y * wad[1] + cA.z * wad[2] + cA.w * wad[3]
                    + cB.x * wad[4] + cB.y * wad[5] + cB.z * wad[6] + cB.w * wad[7];
            p = dpp_add<QXOR1>(p);
            p = dpp_add<QXOR2>(p);
            p = dpp_add<HMIRR>(p);
            if ((tid & 7) == 0) s_c[k][hc] = p + b1;
        }
    }
    __syncthreads();   // the only barrier

    // ---------------- per-wave flash loop over own batch ------------------------
    const int b    = b0 + wid;
    const int len  = lens[b];
    const bool uni = (len == 0);
    const int nrow = uni ? HS : len;          // len==0: uniform mean over all rows
    const int nt   = (nrow + 15) >> 4;
    const int lc   = lane & 15, lg = lane >> 4;
    const float* hb = hist + (size_t)b * (HS * DIMV);

    short8 b00 = *(const short8*)&s_Mt[wid][lc * 64        + ((lg)     ^ (lc & 7)) * 8];
    short8 b01 = *(const short8*)&s_Mt[wid][lc * 64        + ((4 + lg) ^ (lc & 7)) * 8];
    short8 b10 = *(const short8*)&s_Mt[wid][(16 + lc) * 64 + ((lg)     ^ (lc & 7)) * 8];
    short8 b11 = *(const short8*)&s_Mt[wid][(16 + lc) * 64 + ((4 + lg) ^ (lc & 7)) * 8];
    const float c0  = s_c[wid][lc],        c1  = s_c[wid][16 + lc];
    const float w20 = W2[lc] * 0.125f,     w21 = W2[16 + lc] * 0.125f;  // fold 1/sqrt(64)

    float m_run = -3.0e38f, l_acc = 0.f;
    float o0[8] = {0.f, 0.f, 0.f, 0.f, 0.f, 0.f, 0.f, 0.f};
    float o1[8] = {0.f, 0.f, 0.f, 0.f, 0.f, 0.f, 0.f, 0.f};

    // -------- software pipeline: prefetch tile 0, then issue rt+1 each iter -----
    int i0 = lc;
    if (i0 > nrow - 1) i0 = nrow - 1;
    const float* ap0 = hb + i0 * 64 + lg * 8;
    float4 A00 = *(const float4*)ap0;
    float4 A01 = *(const float4*)(ap0 + 4);
    float4 A10 = *(const float4*)(ap0 + 32);
    float4 A11 = *(const float4*)(ap0 + 36);

    for (int rt = 0; rt < nt; ++rt) {         // wave-uniform trip count
        // issue NEXT tile's loads first (clamped -> always in-bounds, no branch)
        int inx = (rt + 1) * 16 + lc;
        if (inx > nrow - 1) inx = nrow - 1;
        const float* apn = hb + inx * 64 + lg * 8;
        float4 N00 = *(const float4*)apn;
        float4 N01 = *(const float4*)(apn + 4);
        float4 N10 = *(const float4*)(apn + 32);
        float4 N11 = *(const float4*)(apn + 36);

        union { uint4 u; short8 s8; } u0, u1;
        u0.u = make_uint4(cvt2(A00.x, A00.y), cvt2(A00.z, A00.w),
                          cvt2(A01.x, A01.y), cvt2(A01.z, A01.w));
        u1.u = make_uint4(cvt2(A10.x, A10.y), cvt2(A10.z, A10.w),
                          cvt2(A11.x, A11.y), cvt2(A11.z, A11.w));

        f32x4 acc0 = {c0, c0, c0, c0};
        acc0 = __builtin_amdgcn_mfma_f32_16x16x32_bf16(u0.s8, b00, acc0, 0, 0, 0);
        acc0 = __builtin_amdgcn_mfma_f32_16x16x32_bf16(u1.s8, b01, acc0, 0, 0, 0);
        f32x4 acc1 = {c1, c1, c1, c1};
        acc1 = __builtin_amdgcn_mfma_f32_16x16x32_bf16(u0.s8, b10, acc1, 0, 0, 0);
        acc1 = __builtin_amdgcn_mfma_f32_16x16x32_bf16(u1.s8, b11, acc1, 0, 0, 0);

        float p[4];
        #pragma unroll
        for (int r = 0; r < 4; ++r)
            p[r] = fmaxf(acc0[r], 0.f) * w20 + fmaxf(acc1[r], 0.f) * w21;  // scaled score
        #pragma unroll
        for (int r = 0; r < 4; ++r) {         // cyclic 16-lane reduce: ALL lanes get sum
            p[r] = dpp_add<ROR1>(p[r]);
            p[r] = dpp_add<ROR2>(p[r]);
            p[r] = dpp_add<ROR4>(p[r]);
            p[r] = dpp_add<ROR8>(p[r]);
        }
        #pragma unroll
        for (int r = 0; r < 4; ++r) {         // mask + uniform override
            int row = rt * 16 + lg * 4 + r;
            p[r] = (row < nrow) ? (uni ? 0.f : p[r]) : -4.0e9f;
        }
        float tmax = fmaxf(fmaxf(p[0], p[1]), fmaxf(p[2], p[3]));
        tmax = fmaxf(tmax, swz_xor16(tmax));
        tmax = fmaxf(tmax, __shfl_xor(tmax, 32));
        tmax = rfl(tmax);                     // exec-uniform running max decision
        if (tmax > m_run + 8.f) {             // T13 defer-rescale
            float sf = __expf(m_run - tmax);  // first tile: exp(-inf) = 0
            #pragma unroll
            for (int j = 0; j < 8; ++j) { o0[j] *= sf; o1[j] *= sf; }
            l_acc *= sf;
            m_run = tmax;
        }
        float e[4];
        #pragma unroll
        for (int r = 0; r < 4; ++r) e[r] = __expf(p[r] - m_run);  // masked -> 0
        l_acc += (e[0] + e[1]) + (e[2] + e[3]);

        // weight for THIS lane's row (row = rt*16+lc): select e[lc&3], pull from
        // lane (lc&3) + 16*(lc>>2)
        float t0 = (lc & 1) ? e[1] : e[0];
        float t1 = (lc & 1) ? e[3] : e[2];
        float es = (lc & 2) ? t1 : t0;
        int   src = (((lc & 3) | ((lc >> 2) << 4)) << 2);
        float wrow = __int_as_float(
            __builtin_amdgcn_ds_bpermute(src, __float_as_int(es)));

        o0[0] = fmaf(wrow, A00.x, o0[0]); o0[1] = fmaf(wrow, A00.y, o0[1]);
        o0[2] = fmaf(wrow, A00.z, o0[2]); o0[3] = fmaf(wrow, A00.w, o0[3]);
        o0[4] = fmaf(wrow, A01.x, o0[4]); o0[5] = fmaf(wrow, A01.y, o0[5]);
        o0[6] = fmaf(wrow, A01.z, o0[6]); o0[7] = fmaf(wrow, A01.w, o0[7]);
        o1[0] = fmaf(wrow, A10.x, o1[0]); o1[1] = fmaf(wrow, A10.y, o1[1]);
        o1[2] = fmaf(wrow, A10.z, o1[2]); o1[3] = fmaf(wrow, A10.w, o1[3]);
        o1[4] = fmaf(wrow, A11.x, o1[4]); o1[5] = fmaf(wrow, A11.y, o1[5]);
        o1[6] = fmaf(wrow, A11.z, o1[6]); o1[7] = fmaf(wrow, A11.w, o1[7]);

        A00 = N00; A01 = N01; A10 = N10; A11 = N11;   // advance pipeline
    }

    // ---------------- finalize: den over lg; o over the 16 rows (lc) ------------
    l_acc += swz_xor16(l_acc);
    l_acc += __shfl_xor(l_acc, 32);
    const float inv = 1.0f / l_acc;
    #pragma unroll
    for (int j = 0; j < 8; ++j) {
        float x = o0[j];
        x = dpp_add<ROR1>(x); x = dpp_add<ROR2>(x);
        x = dpp_add<ROR4>(x); x = dpp_add<ROR8>(x);
        o0[j] = x * inv;
        float y = o1[j];
        y = dpp_add<ROR1>(y); y = dpp_add<ROR2>(y);
        y = dpp_add<ROR4>(y); y = dpp_add<ROR8>(y);
        o1[j] = y * inv;
    }
    if (lc == 0) {                            // lanes 0,16,32,48: d = lg*8.. & 32+lg*8..
        float* op = out + (size_t)b * DIMV + lg * 8;
        *(float4*)op        = make_float4(o0[0], o0[1], o0[2], o0[3]);
        *(float4*)(op + 4)  = make_float4(o0[4], o0[5], o0[6], o0[7]);
        *(float4*)(op + 32) = make_float4(o1[0], o1[1], o1[2], o1[3]);
        *(float4*)(op + 36) = make_float4(o1[4], o1[5], o1[6], o1[7]);
    }
}

extern "C" void kernel_launch(void* const* d_in, const int* in_sizes, int n_in,
                              void* d_out, int out_size, void* d_ws, size_t ws_size,
                              hipStream_t stream) {
    const float* cand = (const float*)d_in[0];
    const float* hist = (const float*)d_in[1];
    const int*   lens = (const int*)d_in[2];
    const float* W1   = (const float*)d_in[3];
    const float* B1   = (const float*)d_in[4];
    const float* W2   = (const float*)d_in[5];
    const float* B2   = (const float*)d_in[6];
    float* out = (float*)d_out;

    const int B = in_sizes[0] / DIMV;     // 4096
    const int GRID = B / NBPB;            // 1024 blocks x 4 waves = 4096 waves
    din_attn_kernel<<<GRID, NTH, 0, stream>>>(cand, hist, lens, W1, B1, W2, B2, out);
}